// Round 1
// baseline (93.919 us; speedup 1.0000x reference)
//
#include <hip/hip_runtime.h>

#define TILE_W 32
#define TILE_H 8
#define HALO 3
#define SW_ (TILE_W + 2*HALO)   // 38
#define SH_ (TILE_H + 2*HALO)   // 14
#define H_IMG 512
#define W_IMG 512
#define C_IMG 3

__device__ __forceinline__ int reflect_idx(int q, int n) {
    q = (q < 0) ? -q : q;
    q = (q >= n) ? (2 * n - 2 - q) : q;
    return q;
}

__global__ __launch_bounds__(256) void AdaptiveFilter_71416716198124_kernel(
    const float* __restrict__ x,
    const float* __restrict__ g,
    const float* __restrict__ w0,
    float* __restrict__ out)
{
    __shared__ float sg[C_IMG][SH_][SW_];
    __shared__ float sx[C_IMG][SH_][SW_];

    const int b  = blockIdx.z;
    const int h0 = blockIdx.y * TILE_H;
    const int w0c = blockIdx.x * TILE_W;
    const int tid = threadIdx.y * TILE_W + threadIdx.x;

    const int plane = H_IMG * W_IMG;
    const float* gb = g + (size_t)b * C_IMG * plane;
    const float* xb = x + (size_t)b * C_IMG * plane;

    // Stage tile + halo (reflect at image borders) into LDS.
    for (int idx = tid; idx < C_IMG * SH_ * SW_; idx += TILE_W * TILE_H) {
        int c = idx / (SH_ * SW_);
        int r = idx - c * (SH_ * SW_);
        int sh = r / SW_;
        int sw = r - sh * SW_;
        int gh = reflect_idx(h0 + sh - HALO, H_IMG);
        int gw = reflect_idx(w0c + sw - HALO, W_IMG);
        int off = c * plane + gh * W_IMG + gw;
        sg[c][sh][sw] = gb[off];
        sx[c][sh][sw] = xb[off];
    }
    __syncthreads();

    const int lx = threadIdx.x, ly = threadIdx.y;
    const int h = h0 + ly, w = w0c + lx;

    // 16 stored half-kernel logits, contiguous per pixel (64B -> 4x float4).
    const float4* wp = (const float4*)(w0 + ((size_t)((b * plane) + h * W_IMG + w) << 4));
    float4 a0 = wp[0], a1 = wp[1], a2 = wp[2], a3 = wp[3];
    float wv[16] = {a0.x, a0.y, a0.z, a0.w, a1.x, a1.y, a1.z, a1.w,
                    a2.x, a2.y, a2.z, a2.w, a3.x, a3.y, a3.z, a3.w};
    float mx = wv[0];
    #pragma unroll
    for (int i = 1; i < 16; i++) mx = fmaxf(mx, wv[i]);

    const float gc0 = sg[0][ly + HALO][lx + HALO];
    const float gc1 = sg[1][ly + HALO][lx + HALO];
    const float gc2 = sg[2][ly + HALO][lx + HALO];

    float n0 = 0.f, n1 = 0.f, n2 = 0.f, den = 0.f;
    // Softmax denominator cancels in num/den: wt = exp(l - max - 50*dist).
    #pragma unroll
    for (int i = 0; i < 7; i++) {
        const int mi = (i < 4) ? i : 6 - i;
        #pragma unroll
        for (int j = 0; j < 7; j++) {
            const int mj = (j < 4) ? j : 6 - j;
            float d0 = fabsf(sg[0][ly + i][lx + j] - gc0);
            float d1 = fabsf(sg[1][ly + i][lx + j] - gc1);
            float d2 = fabsf(sg[2][ly + i][lx + j] - gc2);
            float s = d0 + d1 + d2;
            float wt = __expf(wv[mi * 4 + mj] - mx - 50.0f * (s * s));
            n0 = fmaf(sx[0][ly + i][lx + j], wt, n0);
            n1 = fmaf(sx[1][ly + i][lx + j], wt, n1);
            n2 = fmaf(sx[2][ly + i][lx + j], wt, n2);
            den += wt;
        }
    }
    const float inv = 1.0f / den;
    size_t ob = (size_t)b * C_IMG * plane + (size_t)h * W_IMG + w;
    out[ob]             = n0 * inv;
    out[ob + plane]     = n1 * inv;
    out[ob + 2 * plane] = n2 * inv;
}

extern "C" void kernel_launch(void* const* d_in, const int* in_sizes, int n_in,
                              void* d_out, int out_size, void* d_ws, size_t ws_size,
                              hipStream_t stream) {
    const float* x  = (const float*)d_in[0];
    const float* g  = (const float*)d_in[1];
    const float* w0 = (const float*)d_in[2];
    float* out = (float*)d_out;

    dim3 block(TILE_W, TILE_H, 1);
    dim3 grid(W_IMG / TILE_W, H_IMG / TILE_H, 2);
    AdaptiveFilter_71416716198124_kernel<<<grid, block, 0, stream>>>(x, g, w0, out);
}